// Round 5
// baseline (50.836 us; speedup 1.0000x reference)
//
#include <hip/hip_runtime.h>
#include <math.h>

#define D 40
#define NN 1024
#define BB 2
#define WIN 128
#define RSH 24              // dwords per h row: 20 data + 4 swizzle pad
#define HBUF 3104           // 128*24 + 32 guard dwords (zeroed)

typedef __attribute__((ext_vector_type(8))) _Float16 f16x8;
typedef __attribute__((ext_vector_type(4))) float f32x4;

__device__ __forceinline__ unsigned int pk16(float a, float b) {
    return __builtin_bit_cast(unsigned int, __builtin_amdgcn_cvt_pkrtz(a, b));
}

// gelu = a - a * sigmoid-ish: a - a/(exp2(a*(c1*a^2+c0))+1); 5 VALU + 2 trans
__device__ __forceinline__ float gelu_tanh(float a) {
    float u = a * a;
    float t1 = fmaf(0.10294366f, u, 2.3022083f);   // 2*0.7978845608*log2(e)*(1, 0.044715)
    float e = __builtin_amdgcn_exp2f(a * t1);
    float r = __builtin_amdgcn_rcpf(e + 1.0f);
    return fmaf(-a, r, a);
}

// ai = x @ W1[:D] + b1, aj = x @ W1[D:]; block 0 also packs W2 fp16 MFMA fragments
__global__ __launch_bounds__(64) void precompute_kernel(
    const float* __restrict__ x, const float* __restrict__ W1,
    const float* __restrict__ b1, const float* __restrict__ W2,
    float* __restrict__ ai, float* __restrict__ aj, uint4* __restrict__ w2f) {
    int r = blockIdx.x;
    int t = threadIdx.x;
    __shared__ float xr[D];
    if (t < D) xr[t] = x[(size_t)r * D + t];
    __syncthreads();
    if (t < D) {
        float s1 = b1[t];
        float s2 = 0.0f;
#pragma unroll
        for (int k = 0; k < D; ++k) {
            float xv = xr[k];
            s1 = fmaf(xv, W1[k * D + t], s1);
            s2 = fmaf(xv, W1[(D + k) * D + t], s2);
        }
        ai[(size_t)r * D + t] = s1;
        aj[(size_t)r * D + t] = s2;
    }
    if (r == 0) {
        const int lr = t & 15, lg = t >> 4;
#pragma unroll
        for (int nt = 0; nt < 3; ++nt)
#pragma unroll
            for (int kt = 0; kt < 2; ++kt) {
                unsigned int u[4];
#pragma unroll
                for (int pe = 0; pe < 4; ++pe) {
                    int k0 = kt * 32 + lg * 8 + pe * 2;
                    int dd = nt * 16 + lr;
                    float v0 = (k0 < D && dd < D) ? W2[k0 * D + dd] : 0.0f;
                    float v1 = (k0 + 1 < D && dd < D) ? W2[(k0 + 1) * D + dd] : 0.0f;
                    u[pe] = pk16(v0, v1);
                }
                w2f[(nt * 2 + kt) * 64 + t] = make_uint4(u[0], u[1], u[2], u[3]);
            }
    }
}

__global__ __launch_bounds__(256, 3) void pair_kernel(
    const float* __restrict__ ai_g, const float* __restrict__ aj_g,
    const uint4* __restrict__ w2f, const float* __restrict__ b2,
    float* __restrict__ out) {
    __shared__ unsigned int lds[2 * HBUF];    // double-buffered fp16 h tile (24.8 KB)
    __shared__ float mbuf[200];               // wave-merge buffer (separate: keeps pads zero)

    const int t = threadIdx.x;
    const int bid = blockIdx.x;
    const int bb = bid & 1;
    const int i1 = bid >> 1;                  // 0..511; block does rows i1 and 1023-i1
    const int w = t >> 6;
    const int l = t & 63;
    const int lr = l & 15;
    const int lg = l >> 4;

    // zero LDS once: swizzle pads + guard must read as 0.0
    for (int idx = t; idx < 2 * HBUF; idx += 256) lds[idx] = 0u;

    f16x8 bfr[3][2];
#pragma unroll
    for (int nt = 0; nt < 3; ++nt)
#pragma unroll
        for (int kt = 0; kt < 2; ++kt)
            bfr[nt][kt] = __builtin_bit_cast(f16x8, w2f[(nt * 2 + kt) * 64 + l]);

    float bv[3];
    bv[0] = b2[lr];
    bv[1] = b2[16 + lr];
    bv[2] = (lr < 8) ? b2[32 + lr] : 0.0f;

    const int jl = t & 127;                   // j within window
    const int kh = t >> 7;                    // 0: k0..19, 1: k20..39
    unsigned int* const hrow = lds + jl * RSH + (jl & 4) + kh * 10;  // + buf*HBUF
    __syncthreads();

    for (int half = 0; half < 2; ++half) {
        const int i = half ? (NN - 1 - i1) : i1;
        const float* __restrict__ ai_row = ai_g + ((size_t)bb * NN + i) * D;
        const float4* air4p = reinterpret_cast<const float4*>(ai_row + kh * 20);
        float4 air4[5];
#pragma unroll
        for (int q = 0; q < 5; ++q) air4[q] = air4p[q];

        float m_run = 0.0f, l_run = 0.0f;
        float o0 = 0.0f, o1 = 0.0f, o2 = 0.0f;
        const int nwin = (i + WIN) >> 7;

        auto stage = [&](int win, int buf) {
            const int jsrc = min((win << 7) + jl, i);
            const float* ajr = aj_g + ((size_t)bb * NN + jsrc) * D + kh * 20;
            unsigned int hw[10];
#pragma unroll
            for (int q = 0; q < 5; ++q) {
                const float4 v = *reinterpret_cast<const float4*>(ajr + q * 4);
                float h0 = gelu_tanh(air4[q].x + v.x);
                float h1 = gelu_tanh(air4[q].y + v.y);
                float h2 = gelu_tanh(air4[q].z + v.z);
                float h3 = gelu_tanh(air4[q].w + v.w);
                hw[2 * q]     = pk16(h0, h1);
                hw[2 * q + 1] = pk16(h2, h3);
            }
            unsigned int* hb = hrow + buf * HBUF;
            if (kh == 0) {
                *reinterpret_cast<uint4*>(hb + 0) = make_uint4(hw[0], hw[1], hw[2], hw[3]);
                *reinterpret_cast<uint4*>(hb + 4) = make_uint4(hw[4], hw[5], hw[6], hw[7]);
                *reinterpret_cast<uint2*>(hb + 8) = make_uint2(hw[8], hw[9]);
            } else {
                *reinterpret_cast<uint2*>(hb + 0) = make_uint2(hw[0], hw[1]);
                *reinterpret_cast<uint4*>(hb + 2) = make_uint4(hw[2], hw[3], hw[4], hw[5]);
                *reinterpret_cast<uint4*>(hb + 6) = make_uint4(hw[6], hw[7], hw[8], hw[9]);
            }
        };

        stage(0, 0);
        __syncthreads();

        for (int win = 0; win < nwin; ++win) {
            const int cur = win & 1;
            const int jbase = win << 7;
            if (win + 1 < nwin) stage(win + 1, cur ^ 1);

            // ---- MFMA: p = h @ W2 (fp16) ----
            f32x4 acc[2][3];
#pragma unroll
            for (int m = 0; m < 2; ++m)
#pragma unroll
                for (int nt = 0; nt < 3; ++nt)
                    acc[m][nt] = (f32x4){0.0f, 0.0f, 0.0f, 0.0f};
            const unsigned int* hbase = lds + cur * HBUF;
#pragma unroll
            for (int m = 0; m < 2; ++m) {
                const int row = (w * 2 + m) * 16 + lr;
                const unsigned int* pA = hbase + row * RSH + (row & 4) + lg * 4;
#pragma unroll
                for (int kt = 0; kt < 2; ++kt) {
                    f16x8 a = __builtin_bit_cast(f16x8,
                        *reinterpret_cast<const uint4*>(pA + kt * 16));
#pragma unroll
                    for (int nt = 0; nt < 3; ++nt)
                        acc[m][nt] = __builtin_amdgcn_mfma_f32_16x16x32_f16(a, bfr[nt][kt], acc[m][nt], 0, 0, 0);
                }
            }

            // ---- ||p||, online softmax, o accumulation ----
            float sv[2][4];
#pragma unroll
            for (int m = 0; m < 2; ++m)
#pragma unroll
                for (int r = 0; r < 4; ++r) {
                    float p0 = acc[m][0][r] + bv[0];
                    float p1 = acc[m][1][r] + bv[1];
                    float p2 = acc[m][2][r] + bv[2];
                    acc[m][0][r] = p0; acc[m][1][r] = p1; acc[m][2][r] = p2;
                    float sq = fmaf(p0, p0, fmaf(p1, p1, p2 * p2));
                    sq += __shfl_xor(sq, 1);
                    sq += __shfl_xor(sq, 2);
                    sq += __shfl_xor(sq, 4);
                    sq += __shfl_xor(sq, 8);
                    int j = jbase + (w * 2 + m) * 16 + lg * 4 + r;
                    sv[m][r] = (j <= i) ? sqrtf(sq) : -1e30f;
                }
            float mx = fmaxf(fmaxf(fmaxf(sv[0][0], sv[0][1]), fmaxf(sv[0][2], sv[0][3])),
                             fmaxf(fmaxf(sv[1][0], sv[1][1]), fmaxf(sv[1][2], sv[1][3])));
            mx = fmaxf(mx, __shfl_xor(mx, 16));
            mx = fmaxf(mx, __shfl_xor(mx, 32));
            float mnew = fmaxf(m_run, mx);
            float scale = __expf(m_run - mnew);
            m_run = mnew;
            float wsum = 0.0f, oa0 = 0.0f, oa1 = 0.0f, oa2 = 0.0f;
#pragma unroll
            for (int m = 0; m < 2; ++m)
#pragma unroll
                for (int r = 0; r < 4; ++r) {
                    float wgt = __expf(sv[m][r] - mnew);   // masked j -> exactly 0
                    wsum += wgt;
                    oa0 = fmaf(wgt, acc[m][0][r], oa0);
                    oa1 = fmaf(wgt, acc[m][1][r], oa1);
                    oa2 = fmaf(wgt, acc[m][2][r], oa2);
                }
            l_run = fmaf(l_run, scale, wsum);
            o0 = fmaf(o0, scale, oa0);
            o1 = fmaf(o1, scale, oa1);
            o2 = fmaf(o2, scale, oa2);
            __syncthreads();
        }

        // ---- reduce across lane subgroups, then merge 4 waves ----
        o0 += __shfl_xor(o0, 16); o0 += __shfl_xor(o0, 32);
        o1 += __shfl_xor(o1, 16); o1 += __shfl_xor(o1, 32);
        o2 += __shfl_xor(o2, 16); o2 += __shfl_xor(o2, 32);
        l_run += __shfl_xor(l_run, 16); l_run += __shfl_xor(l_run, 32);

        if (l < 16) {
            mbuf[w * 48 + lr] = o0;
            mbuf[w * 48 + 16 + lr] = o1;
            if (lr < 8) mbuf[w * 48 + 32 + lr] = o2;
            if (lr == 0) { mbuf[w * 48 + 40] = l_run; mbuf[w * 48 + 41] = m_run; }
        }
        __syncthreads();
        if (t < D) {
            float M = fmaxf(fmaxf(mbuf[41], mbuf[48 + 41]),
                            fmaxf(mbuf[96 + 41], mbuf[144 + 41]));
            float L = 0.0f, val = 0.0f;
#pragma unroll
            for (int ww = 0; ww < 4; ++ww) {
                float c = __expf(mbuf[ww * 48 + 41] - M);
                L = fmaf(c, mbuf[ww * 48 + 40], L);
                val = fmaf(c, mbuf[ww * 48 + t], val);
            }
            out[((size_t)bb * NN + i) * D + t] = val / L;
        }
        __syncthreads();   // mbuf reads done before next half reuses anything
    }
}

extern "C" void kernel_launch(void* const* d_in, const int* in_sizes, int n_in,
                              void* d_out, int out_size, void* d_ws, size_t ws_size,
                              hipStream_t stream) {
    const float* x  = (const float*)d_in[0];
    const float* W1 = (const float*)d_in[1];
    const float* b1 = (const float*)d_in[2];
    const float* W2 = (const float*)d_in[3];
    const float* b2 = (const float*)d_in[4];
    float* out = (float*)d_out;

    float* ai = (float*)d_ws;                         // B*N*D floats
    float* aj = ai + (size_t)BB * NN * D;             // B*N*D floats
    uint4* w2f = (uint4*)(aj + (size_t)BB * NN * D);  // 6*64 uint4

    precompute_kernel<<<BB * NN, 64, 0, stream>>>(x, W1, b1, W2, ai, aj, w2f);
    pair_kernel<<<BB * NN / 2, 256, 0, stream>>>(ai, aj, w2f, b2, out);
}

// Round 6
// 40.675 us; speedup vs baseline: 1.2498x; 1.2498x over previous
//
#include <hip/hip_runtime.h>
#include <math.h>

#define D 40
#define NN 1024
#define BB 2
#define WIN 128
#define RSH 20              // dwords per h row (40 fp16)
#define HBUF 2576           // 128*20 + 16 zeroed guard dwords

typedef __attribute__((ext_vector_type(8))) _Float16 f16x8;
typedef __attribute__((ext_vector_type(4))) float f32x4;

__device__ __forceinline__ unsigned int pk16(float a, float b) {
    return __builtin_bit_cast(unsigned int, __builtin_amdgcn_cvt_pkrtz(a, b));
}

// gelu = a - a/(exp2(a*(c1*a^2+c0))+1); 5 VALU + 2 trans
__device__ __forceinline__ float gelu_tanh(float a) {
    float u = a * a;
    float t1 = fmaf(0.10294366f, u, 2.3022083f);
    float e = __builtin_amdgcn_exp2f(a * t1);
    float r = __builtin_amdgcn_rcpf(e + 1.0f);
    return fmaf(-a, r, a);
}

// ai = x @ W1[:D] + b1, aj = x @ W1[D:]; block 0 packs W2^T fp16 A-fragments
__global__ __launch_bounds__(64) void precompute_kernel(
    const float* __restrict__ x, const float* __restrict__ W1,
    const float* __restrict__ b1, const float* __restrict__ W2,
    float* __restrict__ ai, float* __restrict__ aj, uint4* __restrict__ w2fT) {
    int r = blockIdx.x;
    int t = threadIdx.x;
    __shared__ float xr[D];
    if (t < D) xr[t] = x[(size_t)r * D + t];
    __syncthreads();
    if (t < D) {
        float s1 = b1[t];
        float s2 = 0.0f;
#pragma unroll
        for (int k = 0; k < D; ++k) {
            float xv = xr[k];
            s1 = fmaf(xv, W1[k * D + t], s1);
            s2 = fmaf(xv, W1[(D + k) * D + t], s2);
        }
        ai[(size_t)r * D + t] = s1;
        aj[(size_t)r * D + t] = s2;
    }
    if (r == 0) {
        // A = W2^T: A[m=d, k] = W2[k][d]; lane: m = l&15, k = kt*32 + (l>>4)*8 + e
        const int lr = t & 15, lg = t >> 4;
#pragma unroll
        for (int mt = 0; mt < 3; ++mt)
#pragma unroll
            for (int kt = 0; kt < 2; ++kt) {
                unsigned int u[4];
#pragma unroll
                for (int pe = 0; pe < 4; ++pe) {
                    int k0 = kt * 32 + lg * 8 + pe * 2;
                    int dd = mt * 16 + lr;
                    float v0 = (k0 < D && dd < D) ? W2[k0 * D + dd] : 0.0f;
                    float v1 = (k0 + 1 < D && dd < D) ? W2[(k0 + 1) * D + dd] : 0.0f;
                    u[pe] = pk16(v0, v1);
                }
                w2fT[(mt * 2 + kt) * 64 + t] = make_uint4(u[0], u[1], u[2], u[3]);
            }
    }
}

__global__ __launch_bounds__(256) void pair_kernel(
    const float* __restrict__ ai_g, const float* __restrict__ aj_g,
    const uint4* __restrict__ w2fT, const float* __restrict__ b2,
    float* __restrict__ out) {
    __shared__ unsigned int lds[2 * HBUF];    // double-buffered fp16 h tile (20.6 KB)
    __shared__ float mbuf[224];               // 4 waves x 56

    const int t = threadIdx.x;
    const int bid = blockIdx.x;
    const int bb = bid & 1;
    const int i = NN - 1 - (bid >> 1);        // big rows first
    const int w = t >> 6;
    const int l = t & 63;
    const int lr = l & 15;
    const int lg = l >> 4;

    // zero the guard tails (read by kt=1 over-reach of row 127)
    if (t < 16) { lds[128 * RSH + t] = 0u; lds[HBUF + 128 * RSH + t] = 0u; }

    // W2^T A-fragments
    f16x8 w2t[3][2];
#pragma unroll
    for (int mt = 0; mt < 3; ++mt)
#pragma unroll
        for (int kt = 0; kt < 2; ++kt)
            w2t[mt][kt] = __builtin_bit_cast(f16x8, w2fT[(mt * 2 + kt) * 64 + l]);

    // bias for d = mt*16 + lg*4 + r (0 for d >= 40 so padded rows stay exactly 0)
    float bv2[3][4];
#pragma unroll
    for (int mt = 0; mt < 3; ++mt)
#pragma unroll
        for (int r = 0; r < 4; ++r) {
            int d = mt * 16 + lg * 4 + r;
            bv2[mt][r] = (d < D) ? b2[d] : 0.0f;
        }

    const int jl = t & 127;                   // j within window
    const int kh = t >> 7;                    // 0: k0..19, 1: k20..39
    unsigned int* const hrow = lds + jl * RSH + kh * 10;

    const float* __restrict__ ai_row = ai_g + ((size_t)bb * NN + i) * D;
    const float4* air4p = reinterpret_cast<const float4*>(ai_row + kh * 20);
    float4 air4[5];
#pragma unroll
    for (int q = 0; q < 5; ++q) air4[q] = air4p[q];

    float m_run = 0.0f, l_run = 0.0f;
    float o[3][4];
#pragma unroll
    for (int mt = 0; mt < 3; ++mt)
#pragma unroll
        for (int r = 0; r < 4; ++r) o[mt][r] = 0.0f;

    const int nwin = (i + WIN) >> 7;

    auto stage = [&](int win, int buf) {
        const int jsrc = min((win << 7) + jl, i);
        const float* ajr = aj_g + ((size_t)bb * NN + jsrc) * D + kh * 20;
        unsigned int hw[10];
#pragma unroll
        for (int q = 0; q < 5; ++q) {
            const float4 v = *reinterpret_cast<const float4*>(ajr + q * 4);
            float h0 = gelu_tanh(air4[q].x + v.x);
            float h1 = gelu_tanh(air4[q].y + v.y);
            float h2 = gelu_tanh(air4[q].z + v.z);
            float h3 = gelu_tanh(air4[q].w + v.w);
            hw[2 * q]     = pk16(h0, h1);
            hw[2 * q + 1] = pk16(h2, h3);
        }
        unsigned int* hb = hrow + buf * HBUF;
        if (kh == 0) {
            *reinterpret_cast<uint4*>(hb + 0) = make_uint4(hw[0], hw[1], hw[2], hw[3]);
            *reinterpret_cast<uint4*>(hb + 4) = make_uint4(hw[4], hw[5], hw[6], hw[7]);
            *reinterpret_cast<uint2*>(hb + 8) = make_uint2(hw[8], hw[9]);
        } else {
            *reinterpret_cast<uint2*>(hb + 0) = make_uint2(hw[0], hw[1]);
            *reinterpret_cast<uint4*>(hb + 2) = make_uint4(hw[2], hw[3], hw[4], hw[5]);
            *reinterpret_cast<uint4*>(hb + 6) = make_uint4(hw[6], hw[7], hw[8], hw[9]);
        }
    };

    __syncthreads();   // guard zeroing visible
    stage(0, 0);
    __syncthreads();

    for (int win = 0; win < nwin; ++win) {
        const int cur = win & 1;
        const int jbase = win << 7;
        if (win + 1 < nwin) stage(win + 1, cur ^ 1);

        // ---- MFMA: C'[d, j] = W2^T @ h^T  (A = W2^T, B = h) ----
        const unsigned int* hbase = lds + cur * HBUF;
        f16x8 hf[2][2];
#pragma unroll
        for (int n = 0; n < 2; ++n) {
            const unsigned int* pB = hbase + ((w * 2 + n) * 16 + lr) * RSH + lg * 4;
#pragma unroll
            for (int kt = 0; kt < 2; ++kt)
                hf[n][kt] = __builtin_bit_cast(f16x8,
                    *reinterpret_cast<const uint4*>(pB + kt * 16));
        }
        f32x4 acc[3][2];
#pragma unroll
        for (int mt = 0; mt < 3; ++mt)
#pragma unroll
            for (int n = 0; n < 2; ++n)
                acc[mt][n] = (f32x4){0.0f, 0.0f, 0.0f, 0.0f};
#pragma unroll
        for (int mt = 0; mt < 3; ++mt)
#pragma unroll
            for (int kt = 0; kt < 2; ++kt)
#pragma unroll
                for (int n = 0; n < 2; ++n)
                    acc[mt][n] = __builtin_amdgcn_mfma_f32_16x16x32_f16(
                        w2t[mt][kt], hf[n][kt], acc[mt][n], 0, 0, 0);

        // ---- ||p|| per j (j = lane's lr), online softmax ----
        float sv[2];
#pragma unroll
        for (int n = 0; n < 2; ++n) {
            float sq = 0.0f;
#pragma unroll
            for (int mt = 0; mt < 3; ++mt)
#pragma unroll
                for (int r = 0; r < 4; ++r) {
                    float p = acc[mt][n][r] + bv2[mt][r];
                    acc[mt][n][r] = p;
                    sq = fmaf(p, p, sq);
                }
            sq += __shfl_xor(sq, 16);
            sq += __shfl_xor(sq, 32);
            int j = jbase + (w * 2 + n) * 16 + lr;
            sv[n] = (j <= i) ? __builtin_amdgcn_sqrtf(sq) : -1e30f;
        }
        float mx = fmaxf(sv[0], sv[1]);
        mx = fmaxf(mx, __shfl_xor(mx, 1));
        mx = fmaxf(mx, __shfl_xor(mx, 2));
        mx = fmaxf(mx, __shfl_xor(mx, 4));
        mx = fmaxf(mx, __shfl_xor(mx, 8));
        float mnew = fmaxf(m_run, mx);
        float scale = __expf(m_run - mnew);
        m_run = mnew;
        float w0 = __expf(sv[0] - mnew);      // masked j -> exactly 0
        float w1 = __expf(sv[1] - mnew);
        l_run = fmaf(l_run, scale, w0 + w1);
#pragma unroll
        for (int mt = 0; mt < 3; ++mt)
#pragma unroll
            for (int r = 0; r < 4; ++r)
                o[mt][r] = fmaf(o[mt][r], scale,
                                fmaf(w0, acc[mt][0][r], w1 * acc[mt][1][r]));
        __syncthreads();
    }

    // ---- reduce o over the 16 j-lanes, merge 4 waves ----
#pragma unroll
    for (int mt = 0; mt < 3; ++mt)
#pragma unroll
        for (int r = 0; r < 4; ++r) {
            float v = o[mt][r];
            v += __shfl_xor(v, 1);
            v += __shfl_xor(v, 2);
            v += __shfl_xor(v, 4);
            v += __shfl_xor(v, 8);
            o[mt][r] = v;
        }
    l_run += __shfl_xor(l_run, 1);
    l_run += __shfl_xor(l_run, 2);
    l_run += __shfl_xor(l_run, 4);
    l_run += __shfl_xor(l_run, 8);

    if (lr == 0) {
#pragma unroll
        for (int mt = 0; mt < 3; ++mt)
#pragma unroll
            for (int r = 0; r < 4; ++r) {
                int d = mt * 16 + lg * 4 + r;
                if (d < D) mbuf[w * 56 + d] = o[mt][r];
            }
        if (lg == 0) { mbuf[w * 56 + 48] = l_run; mbuf[w * 56 + 49] = m_run; }
    }
    __syncthreads();
    if (t < D) {
        float M = fmaxf(fmaxf(mbuf[49], mbuf[56 + 49]),
                        fmaxf(mbuf[112 + 49], mbuf[168 + 49]));
        float L = 0.0f, val = 0.0f;
#pragma unroll
        for (int ww = 0; ww < 4; ++ww) {
            float c = __expf(mbuf[ww * 56 + 49] - M);
            L = fmaf(c, mbuf[ww * 56 + 48], L);
            val = fmaf(c, mbuf[ww * 56 + t], val);
        }
        out[((size_t)bb * NN + i) * D + t] = val / L;
    }
}

extern "C" void kernel_launch(void* const* d_in, const int* in_sizes, int n_in,
                              void* d_out, int out_size, void* d_ws, size_t ws_size,
                              hipStream_t stream) {
    const float* x  = (const float*)d_in[0];
    const float* W1 = (const float*)d_in[1];
    const float* b1 = (const float*)d_in[2];
    const float* W2 = (const float*)d_in[3];
    const float* b2 = (const float*)d_in[4];
    float* out = (float*)d_out;

    float* ai = (float*)d_ws;                          // B*N*D floats
    float* aj = ai + (size_t)BB * NN * D;              // B*N*D floats
    uint4* w2fT = (uint4*)(aj + (size_t)BB * NN * D);  // 6*64 uint4

    precompute_kernel<<<BB * NN, 64, 0, stream>>>(x, W1, b1, W2, ai, aj, w2fT);
    pair_kernel<<<BB * NN, 256, 0, stream>>>(ai, aj, w2fT, b2, out);
}

// Round 7
// 39.257 us; speedup vs baseline: 1.2950x; 1.0361x over previous
//
#include <hip/hip_runtime.h>
#include <math.h>

#define D 40
#define NN 1024
#define BB 2

typedef __attribute__((ext_vector_type(8))) _Float16 f16x8;
typedef __attribute__((ext_vector_type(4))) float f32x4;

__device__ __forceinline__ unsigned int pk16(float a, float b) {
    return __builtin_bit_cast(unsigned int, __builtin_amdgcn_cvt_pkrtz(a, b));
}

// gelu = a - a/(exp2(a*(c1*a^2+c0))+1); 5 VALU + 2 trans
__device__ __forceinline__ float gelu_tanh(float a) {
    float u = a * a;
    float t1 = fmaf(0.10294366f, u, 2.3022083f);
    float e = __builtin_amdgcn_exp2f(a * t1);
    float r = __builtin_amdgcn_rcpf(e + 1.0f);
    return fmaf(-a, r, a);
}

// build fp16x8 B-fragment: gelu(air + ajv) for 8 consecutive k
__device__ __forceinline__ f16x8 frag8(float4 a0, float4 a1, float4 x0, float4 x1) {
    float g0 = gelu_tanh(a0.x + x0.x);
    float g1 = gelu_tanh(a0.y + x0.y);
    float g2 = gelu_tanh(a0.z + x0.z);
    float g3 = gelu_tanh(a0.w + x0.w);
    float g4 = gelu_tanh(a1.x + x1.x);
    float g5 = gelu_tanh(a1.y + x1.y);
    float g6 = gelu_tanh(a1.z + x1.z);
    float g7 = gelu_tanh(a1.w + x1.w);
    return __builtin_bit_cast(f16x8,
        make_uint4(pk16(g0, g1), pk16(g2, g3), pk16(g4, g5), pk16(g6, g7)));
}

// ai = x @ W1[:D] + b1, aj = x @ W1[D:]; block 0 packs W2^T fp16 A-fragments
__global__ __launch_bounds__(64) void precompute_kernel(
    const float* __restrict__ x, const float* __restrict__ W1,
    const float* __restrict__ b1, const float* __restrict__ W2,
    float* __restrict__ ai, float* __restrict__ aj, uint4* __restrict__ w2fT) {
    int r = blockIdx.x;
    int t = threadIdx.x;
    __shared__ float xr[D];
    if (t < D) xr[t] = x[(size_t)r * D + t];
    __syncthreads();
    if (t < D) {
        float s1 = b1[t];
        float s2 = 0.0f;
#pragma unroll
        for (int k = 0; k < D; ++k) {
            float xv = xr[k];
            s1 = fmaf(xv, W1[k * D + t], s1);
            s2 = fmaf(xv, W1[(D + k) * D + t], s2);
        }
        ai[(size_t)r * D + t] = s1;
        aj[(size_t)r * D + t] = s2;
    }
    if (r == 0) {
        // A = W2^T: A[m=d, k] = W2[k][d]; lane: m = l&15, k = kt*32 + (l>>4)*8 + e
        const int lr = t & 15, lg = t >> 4;
#pragma unroll
        for (int mt = 0; mt < 3; ++mt)
#pragma unroll
            for (int kt = 0; kt < 2; ++kt) {
                unsigned int u[4];
#pragma unroll
                for (int pe = 0; pe < 4; ++pe) {
                    int k0 = kt * 32 + lg * 8 + pe * 2;
                    int dd = mt * 16 + lr;
                    float v0 = (k0 < D && dd < D) ? W2[k0 * D + dd] : 0.0f;
                    float v1 = (k0 + 1 < D && dd < D) ? W2[(k0 + 1) * D + dd] : 0.0f;
                    u[pe] = pk16(v0, v1);
                }
                w2fT[(mt * 2 + kt) * 64 + t] = make_uint4(u[0], u[1], u[2], u[3]);
            }
    }
}

__global__ void pair_kernel(
    const float* __restrict__ ai_g, const float* __restrict__ aj_g,
    const uint4* __restrict__ w2fT, const float* __restrict__ b2,
    float* __restrict__ out) {
    __shared__ float mbuf[224];               // 4 waves x 56 (only LDS in kernel)

    const int t = threadIdx.x;
    const int bid = blockIdx.x;
    const int bb = bid & 1;
    const int i = NN - 1 - (bid >> 1);        // big rows first
    const int w = t >> 6;
    const int l = t & 63;
    const int lr = l & 15;
    const int lg = l >> 4;

    // W2^T A-fragments (6 x 16B from L2)
    f16x8 w2t[3][2];
#pragma unroll
    for (int mt = 0; mt < 3; ++mt)
#pragma unroll
        for (int kt = 0; kt < 2; ++kt)
            w2t[mt][kt] = __builtin_bit_cast(f16x8, w2fT[(mt * 2 + kt) * 64 + l]);

    // bias for d = mt*16 + lg*4 + r (0 for d >= 40: padded rows stay exactly 0)
    float bv2[3][4];
#pragma unroll
    for (int mt = 0; mt < 3; ++mt)
#pragma unroll
        for (int r = 0; r < 4; ++r) {
            int d = mt * 16 + lg * 4 + r;
            bv2[mt][r] = (d < D) ? b2[d] : 0.0f;
        }

    // ai fragment for this lane's k-slots: k = kt*32 + lg*8 + e
    // (kt=1, lg>=1 reads past row end -> garbage h, killed by zero A-frag)
    const float* air_p = ai_g + ((size_t)bb * NN + i) * D + (lg << 3);
    float4 air[2][2];
    air[0][0] = *reinterpret_cast<const float4*>(air_p);
    air[0][1] = *reinterpret_cast<const float4*>(air_p + 4);
    air[1][0] = *reinterpret_cast<const float4*>(air_p + 32);
    air[1][1] = *reinterpret_cast<const float4*>(air_p + 36);

    const float* aj_b = aj_g + (size_t)bb * NN * D;

    float m_run = 0.0f, l_run = 0.0f;
    float o[3][4];
#pragma unroll
    for (int mt = 0; mt < 3; ++mt)
#pragma unroll
        for (int r = 0; r < 4; ++r) o[mt][r] = 0.0f;

    // each wave takes interleaved 32-j windows: jbase = (q*4 + w)*32
    for (int jbase = w << 5; jbase <= i; jbase += 128) {
        f32x4 acc[3][2];
#pragma unroll
        for (int mt = 0; mt < 3; ++mt)
#pragma unroll
            for (int n = 0; n < 2; ++n)
                acc[mt][n] = (f32x4){0.0f, 0.0f, 0.0f, 0.0f};

#pragma unroll
        for (int n = 0; n < 2; ++n) {
            const int j = jbase + n * 16 + lr;
            const int jsrc = min(j, i);               // masked lanes: finite data
            const float* ajr = aj_b + (size_t)jsrc * D + (lg << 3);
            float4 q0 = *reinterpret_cast<const float4*>(ajr);
            float4 q1 = *reinterpret_cast<const float4*>(ajr + 4);
            float4 q2 = *reinterpret_cast<const float4*>(ajr + 32);
            float4 q3 = *reinterpret_cast<const float4*>(ajr + 36);
            f16x8 B0 = frag8(air[0][0], air[0][1], q0, q1);
            f16x8 B1 = frag8(air[1][0], air[1][1], q2, q3);
#pragma unroll
            for (int mt = 0; mt < 3; ++mt) {
                acc[mt][n] = __builtin_amdgcn_mfma_f32_16x16x32_f16(
                    w2t[mt][0], B0, acc[mt][n], 0, 0, 0);
                acc[mt][n] = __builtin_amdgcn_mfma_f32_16x16x32_f16(
                    w2t[mt][1], B1, acc[mt][n], 0, 0, 0);
            }
        }

        // ---- ||p|| per j (j on lr lanes), online softmax with defer-rescale ----
        float sv[2];
#pragma unroll
        for (int n = 0; n < 2; ++n) {
            float sq = 0.0f;
#pragma unroll
            for (int mt = 0; mt < 3; ++mt)
#pragma unroll
                for (int r = 0; r < 4; ++r) {
                    float p = acc[mt][n][r] + bv2[mt][r];
                    acc[mt][n][r] = p;
                    sq = fmaf(p, p, sq);
                }
            sq += __shfl_xor(sq, 16);
            sq += __shfl_xor(sq, 32);
            int j = jbase + n * 16 + lr;
            sv[n] = (j <= i) ? __builtin_amdgcn_sqrtf(sq) : -1e30f;
        }
        float mx = fmaxf(sv[0], sv[1]);
        mx = fmaxf(mx, __shfl_xor(mx, 1));
        mx = fmaxf(mx, __shfl_xor(mx, 2));
        mx = fmaxf(mx, __shfl_xor(mx, 4));
        mx = fmaxf(mx, __shfl_xor(mx, 8));
        if (mx > m_run) {                      // wave-uniform branch
            float scale = __expf(m_run - mx);
            l_run *= scale;
#pragma unroll
            for (int mt = 0; mt < 3; ++mt)
#pragma unroll
                for (int r = 0; r < 4; ++r) o[mt][r] *= scale;
            m_run = mx;
        }
        float w0 = __expf(sv[0] - m_run);      // masked j -> exactly 0
        float w1 = __expf(sv[1] - m_run);
        l_run += w0 + w1;
#pragma unroll
        for (int mt = 0; mt < 3; ++mt)
#pragma unroll
            for (int r = 0; r < 4; ++r)
                o[mt][r] = fmaf(w0, acc[mt][0][r], fmaf(w1, acc[mt][1][r], o[mt][r]));
    }

    // ---- reduce o over the 16 j-lanes, merge 4 waves ----
#pragma unroll
    for (int mt = 0; mt < 3; ++mt)
#pragma unroll
        for (int r = 0; r < 4; ++r) {
            float v = o[mt][r];
            v += __shfl_xor(v, 1);
            v += __shfl_xor(v, 2);
            v += __shfl_xor(v, 4);
            v += __shfl_xor(v, 8);
            o[mt][r] = v;
        }
    l_run += __shfl_xor(l_run, 1);
    l_run += __shfl_xor(l_run, 2);
    l_run += __shfl_xor(l_run, 4);
    l_run += __shfl_xor(l_run, 8);

    if (lr == 0) {
#pragma unroll
        for (int mt = 0; mt < 3; ++mt)
#pragma unroll
            for (int r = 0; r < 4; ++r) {
                int d = mt * 16 + lg * 4 + r;
                if (d < D) mbuf[w * 56 + d] = o[mt][r];
            }
        if (lg == 0) { mbuf[w * 56 + 48] = l_run; mbuf[w * 56 + 49] = m_run; }
    }
    __syncthreads();
    if (t < D) {
        float M = fmaxf(fmaxf(mbuf[49], mbuf[56 + 49]),
                        fmaxf(mbuf[112 + 49], mbuf[168 + 49]));
        float L = 0.0f, val = 0.0f;
#pragma unroll
        for (int ww = 0; ww < 4; ++ww) {
            float c = __expf(mbuf[ww * 56 + 49] - M);
            L = fmaf(c, mbuf[ww * 56 + 48], L);
            val = fmaf(c, mbuf[ww * 56 + t], val);
        }
        out[((size_t)bb * NN + i) * D + t] = val / L;
    }
}

extern "C" void kernel_launch(void* const* d_in, const int* in_sizes, int n_in,
                              void* d_out, int out_size, void* d_ws, size_t ws_size,
                              hipStream_t stream) {
    const float* x  = (const float*)d_in[0];
    const float* W1 = (const float*)d_in[1];
    const float* b1 = (const float*)d_in[2];
    const float* W2 = (const float*)d_in[3];
    const float* b2 = (const float*)d_in[4];
    float* out = (float*)d_out;

    float* ai = (float*)d_ws;                          // B*N*D floats
    float* aj = ai + (size_t)BB * NN * D;              // B*N*D floats
    uint4* w2fT = (uint4*)(aj + (size_t)BB * NN * D);  // 6*64 uint4 (also OOB pad)

    precompute_kernel<<<BB * NN, 64, 0, stream>>>(x, W1, b1, W2, ai, aj, w2fT);
    pair_kernel<<<BB * NN, 256, 0, stream>>>(ai, aj, w2fT, b2, out);
}